// Round 4
// baseline (551.089 us; speedup 1.0000x reference)
//
#include <hip/hip_runtime.h>
#include <math.h>

// ---------------------------------------------------------------------------
// IG_RGCN forward on MI355X. Round 8: occupancy + A-prefetch for all GEMMs.
//  - gemm_mfma templated on (K, aKind) ∈ {(128,fp32),(256,bf16),(768,agg)}:
//    * LDS halved to 16 KB (B staged per 64-K chunk) -> 10 blocks/CU ceiling
//    * K<=256: ALL A-fragments prefetched to VGPRs before first barrier
//    * K==768: chunk's 2 A-frags issued before the chunk barriers (latency
//      hidden under stage+sync)
//  - attn_mfma same treatment (K=128 fixed).
//  - CSR build, agg, combine, prep unchanged from round 7 (546.8 us).
// ---------------------------------------------------------------------------

typedef short s16x8 __attribute__((ext_vector_type(8)));
typedef float f32x4 __attribute__((ext_vector_type(4)));

__device__ __forceinline__ ushort f2bf(float f) {
  unsigned u = __float_as_uint(f);
  return (ushort)((u + 0x7FFFu + ((u >> 16) & 1u)) >> 16);
}
__device__ __forceinline__ float bf2f(unsigned hbits) {
  return __uint_as_float(hbits << 16);
}
__device__ __forceinline__ unsigned pack2(float lo, float hi) {
  return (unsigned)f2bf(lo) | ((unsigned)f2bf(hi) << 16);
}

// ---- one-shot weight prep: 8 tensors, W[r][K][128] fp32 -> Wt[r][128][K] bf16
struct PrepAll {
  const float* src[8];
  ushort* dst[8];
  int K[8];
  int total[8];   // R*K*128
};

__global__ __launch_bounds__(256) void prep_all(PrepAll P)
{
  int t = blockIdx.z;
  int off = blockIdx.x * 256 + threadIdx.x;
  if (off >= P.total[t]) return;
  int K = P.K[t];
  int k = off % K;
  int n = (off / K) & 127;
  int r = off / (K * 128);
  P.dst[t][off] = f2bf(P.src[t][((size_t)r * K + k) * 128 + n]);
}

struct GemmDesc {
  const void* A; int lda; size_t aStride; int aKind;   // 0 fp32, 1 bf16, 2 virtual agg
  const ushort* Wt; size_t wStride;                    // [128][K] bf16 per relation
  const float* bias; int biasStride;
  void* C; int ldc; size_t cStride; int cKind;         // 0 fp32, 1 bf16
  int M, K, relu;
  const ushort* aggM; const ushort* aggS; const float* invdeg;
  size_t aggStride; int invStride;
  // optional fused gather (embed only): fill C cols 128..255 with bf16(tss|rs)[nid]
  const int* gnid; const float* gtss; const float* grs;
};

// Load one A fragment (16 bf16 k-values for this lane's row) at k-offset k0.
template<int AKIND>
__device__ __forceinline__ uint4 loadA(const void* Ab, const ushort* AgM,
                                       const ushort* AgS, int lda, int row,
                                       bool rowOK, int k0, int quad, float idg)
{
  uint4 pk = make_uint4(0u, 0u, 0u, 0u);
  if (rowOK) {
    if constexpr (AKIND == 1) {
      pk = *(const uint4*)((const ushort*)Ab + (size_t)row * lda + k0 + quad * 8);
    } else if constexpr (AKIND == 0) {
      const float* A32 = (const float*)Ab;
      float4 fa = *(const float4*)(A32 + (size_t)row * lda + k0 + quad * 8);
      float4 fb = *(const float4*)(A32 + (size_t)row * lda + k0 + quad * 8 + 4);
      pk.x = pack2(fa.x, fa.y); pk.y = pack2(fa.z, fa.w);
      pk.z = pack2(fb.x, fb.y); pk.w = pack2(fb.z, fb.w);
    } else {                               // virtual [mx | sum*invdeg | sum]
      int seg = k0 >> 8;
      int jj  = (k0 & 255) + quad * 8;
      const ushort* Ag = (seg == 0) ? AgM : AgS;
      pk = *(const uint4*)(Ag + (size_t)row * 256 + jj);
      if (seg == 1) {
        pk.x = pack2(bf2f(pk.x & 0xFFFFu) * idg, bf2f(pk.x >> 16) * idg);
        pk.y = pack2(bf2f(pk.y & 0xFFFFu) * idg, bf2f(pk.y >> 16) * idg);
        pk.z = pack2(bf2f(pk.z & 0xFFFFu) * idg, bf2f(pk.z >> 16) * idg);
        pk.w = pack2(bf2f(pk.w & 0xFFFFu) * idg, bf2f(pk.w >> 16) * idg);
      }
    }
  }
  return pk;
}

// Core: C[M,128] = act(A[M,K] @ W + b). 64 rows/block, 16 rows/wave.
// B staged per 64-K chunk in MFMA-fragment order (16 KB LDS):
// Bs[(ks*8+j)*64+lane] <- Wt[col=j*16+(lane&15)][k=c*64+ks*32+(lane>>4)*8..+8]
template<int K, int AKIND>
__device__ __forceinline__ void gemm_core(const GemmDesc& d, int r, ushort* Bs)
{
  constexpr int NC = K / 64;     // 64-K staging chunks
  constexpr int NF = K / 32;     // A fragments per row

  const int tid = threadIdx.x;
  const int wave = tid >> 6, lane = tid & 63;
  const int m16 = lane & 15, quad = lane >> 4;
  const int rowBase = blockIdx.x * 64;
  const int row = rowBase + wave * 16 + m16;
  const bool rowOK = row < d.M;
  const ushort* Wt = d.Wt + (size_t)r * d.wStride;

  const void* Ab = (const char*)d.A +
      (size_t)r * d.aStride * (AKIND == 0 ? sizeof(float) : sizeof(ushort));
  const ushort* AgM = d.aggM + (size_t)r * d.aggStride;
  const ushort* AgS = d.aggS + (size_t)r * d.aggStride;

  float idg = 1.f;
  if (AKIND == 2 && rowOK) idg = d.invdeg[(size_t)r * d.invStride + row];

  f32x4 acc[8];
  #pragma unroll
  for (int j = 0; j < 8; ++j)
    #pragma unroll
    for (int p = 0; p < 4; ++p) acc[j][p] = 0.f;

  // A prefetch: all fragments for K<=256 (static-indexed -> registers)
  uint4 pkAll[(K <= 256) ? NF : 2];
  if constexpr (K <= 256) {
    #pragma unroll
    for (int f = 0; f < NF; ++f)
      pkAll[f] = loadA<AKIND>(Ab, AgM, AgS, d.lda, row, rowOK, f * 32, quad, idg);
  }

  #pragma unroll
  for (int c = 0; c < NC; ++c) {
    if constexpr (K > 256) {   // issue this chunk's A before barriers
      pkAll[0] = loadA<AKIND>(Ab, AgM, AgS, d.lda, row, rowOK, c * 64,      quad, idg);
      pkAll[1] = loadA<AKIND>(Ab, AgM, AgS, d.lda, row, rowOK, c * 64 + 32, quad, idg);
    }
    if (c) __syncthreads();                 // waves done reading prev chunk
    #pragma unroll
    for (int i = 0; i < 4; ++i) {           // stage 1024 frags (16 KB)
      int q = tid + 256 * i;
      int col = ((q >> 6) & 7) * 16 + (q & 15);
      int kk  = c * 64 + (q >> 9) * 32 + ((q >> 4) & 3) * 8;
      *(uint4*)&Bs[q * 8] = *(const uint4*)(Wt + (size_t)col * K + kk);
    }
    __syncthreads();

    #pragma unroll
    for (int ks = 0; ks < 2; ++ks) {
      uint4 pk = (K <= 256) ? pkAll[c * 2 + ks] : pkAll[ks];
      s16x8 af = *(s16x8*)&pk;
      #pragma unroll
      for (int j = 0; j < 8; ++j) {
        s16x8 bf = *(const s16x8*)&Bs[((ks * 8 + j) * 64 + lane) * 8];
        acc[j] = __builtin_amdgcn_mfma_f32_16x16x32_bf16(af, bf, acc[j], 0, 0, 0);
      }
    }
  }

  const float* bias = d.bias + (size_t)r * d.biasStride;
  float bcol[8];
  #pragma unroll
  for (int j = 0; j < 8; ++j) bcol[j] = bias[j * 16 + m16];

  #pragma unroll
  for (int p = 0; p < 4; ++p) {
    int grow = rowBase + wave * 16 + quad * 4 + p;
    if (grow >= d.M) continue;
    if (d.cKind == 0) {
      float* Crow = (float*)d.C + (size_t)r * d.cStride + (size_t)grow * d.ldc;
      #pragma unroll
      for (int j = 0; j < 8; ++j) {
        float v = acc[j][p] + bcol[j];
        if (d.relu) v = fmaxf(v, 0.f);
        Crow[j * 16 + m16] = v;
      }
    } else {
      ushort* Crow = (ushort*)d.C + (size_t)r * d.cStride + (size_t)grow * d.ldc;
      #pragma unroll
      for (int j = 0; j < 8; ++j) {
        float v = acc[j][p] + bcol[j];
        if (d.relu) v = fmaxf(v, 0.f);
        Crow[j * 16 + m16] = f2bf(v);
      }
    }
  }

  // fused gather (embed only): C cols 128..255 <- bf16(tss[nid] | rs[nid])
  if constexpr (K == 128) {
    if (d.gnid) {
      #pragma unroll
      for (int i = 0; i < 8; ++i) {
        int q = tid + 256 * i;            // 2048 tasks: 64 rows x 32 chunks
        int grow = rowBase + (q >> 5);
        int c = q & 31;
        if (grow >= d.M) continue;
        int id = d.gnid[grow];
        float4 v = (c < 16) ? *(const float4*)(d.gtss + (size_t)id * 64 + c * 4)
                            : *(const float4*)(d.grs  + (size_t)id * 64 + (c - 16) * 4);
        uint2 g; g.x = pack2(v.x, v.y); g.y = pack2(v.z, v.w);
        *(uint2*)((ushort*)d.C + (size_t)grow * d.ldc + 128 + c * 4) = g;
      }
    }
  }
}

__global__ __launch_bounds__(256, 4) void gemm_mfma(GemmDesc d0, GemmDesc d1)
{
  __shared__ __align__(16) ushort Bs[1024 * 8];   // 16 KB
  const GemmDesc& d = blockIdx.z ? d1 : d0;
  const int r = blockIdx.y;
  if (d.K == 128)      gemm_core<128, 0>(d, r, Bs);
  else if (d.K == 256) gemm_core<256, 1>(d, r, Bs);
  else                 gemm_core<768, 2>(d, r, Bs);
}

// ---- MFMA semantic attention: wsum[r] += sum_n tanh(z[r,n,:]@w1+b1)@w2
// Same structure: K=128, fp32 A fully prefetched, B staged per 64-K chunk.
__global__ __launch_bounds__(256, 4) void attn_mfma(
    const float* __restrict__ z, const ushort* __restrict__ w1t,
    const float* __restrict__ b1, const float* __restrict__ w2,
    int N, float* __restrict__ wsum)
{
  const int r = blockIdx.y;
  const float* zr = z + (size_t)r * N * 128;
  __shared__ __align__(16) ushort Bs[1024 * 8];   // 16 KB

  const int tid = threadIdx.x;
  const int wave = tid >> 6, lane = tid & 63;
  const int m16 = lane & 15, quad = lane >> 4;
  const int rowBase = blockIdx.x * 64;
  const int row = rowBase + wave * 16 + m16;
  const bool rowOK = row < N;

  f32x4 acc[8];
  #pragma unroll
  for (int j = 0; j < 8; ++j)
    #pragma unroll
    for (int p = 0; p < 4; ++p) acc[j][p] = 0.f;

  uint4 pkAll[4];
  #pragma unroll
  for (int f = 0; f < 4; ++f) {
    uint4 pk = make_uint4(0u, 0u, 0u, 0u);
    if (rowOK) {
      float4 fa = *(const float4*)(zr + (size_t)row * 128 + f * 32 + quad * 8);
      float4 fb = *(const float4*)(zr + (size_t)row * 128 + f * 32 + quad * 8 + 4);
      pk.x = pack2(fa.x, fa.y); pk.y = pack2(fa.z, fa.w);
      pk.z = pack2(fb.x, fb.y); pk.w = pack2(fb.z, fb.w);
    }
    pkAll[f] = pk;
  }

  #pragma unroll
  for (int c = 0; c < 2; ++c) {
    if (c) __syncthreads();
    #pragma unroll
    for (int i = 0; i < 4; ++i) {
      int q = tid + 256 * i;
      int col = ((q >> 6) & 7) * 16 + (q & 15);
      int kk  = c * 64 + (q >> 9) * 32 + ((q >> 4) & 3) * 8;
      *(uint4*)&Bs[q * 8] = *(const uint4*)(w1t + (size_t)col * 128 + kk);
    }
    __syncthreads();

    #pragma unroll
    for (int ks = 0; ks < 2; ++ks) {
      s16x8 af = *(s16x8*)&pkAll[c * 2 + ks];
      #pragma unroll
      for (int j = 0; j < 8; ++j) {
        s16x8 bf = *(const s16x8*)&Bs[((ks * 8 + j) * 64 + lane) * 8];
        acc[j] = __builtin_amdgcn_mfma_f32_16x16x32_bf16(af, bf, acc[j], 0, 0, 0);
      }
    }
  }

  float b1c[8], w2c[8];
  #pragma unroll
  for (int j = 0; j < 8; ++j) { b1c[j] = b1[j * 16 + m16]; w2c[j] = w2[j * 16 + m16]; }

  float local = 0.f;
  #pragma unroll
  for (int p = 0; p < 4; ++p) {
    int grow = rowBase + wave * 16 + quad * 4 + p;
    if (grow >= N) continue;
    #pragma unroll
    for (int j = 0; j < 8; ++j)
      local += tanhf(acc[j][p] + b1c[j]) * w2c[j];
  }
  #pragma unroll
  for (int o = 32; o > 0; o >>= 1) local += __shfl_down(local, o);
  __shared__ float red[4];
  if (lane == 0) red[wave] = local;
  __syncthreads();
  if (tid == 0) atomicAdd(&wsum[r], red[0] + red[1] + red[2] + red[3]);
}

// ---------------- CSR build (batched over R=3 relations) ----------------
__global__ void count_deg(const int* __restrict__ edst, int E, int N, int* __restrict__ deg)
{
  int e = blockIdx.x * blockDim.x + threadIdx.x;
  int r = blockIdx.y;
  if (e < E) atomicAdd(&deg[r * N + edst[(size_t)r * E + e]], 1);
}

// single-block exclusive scan, 4096 elems/iter; zeroes cursor (aliases deg)
__global__ __launch_bounds__(1024) void scan_kernel(
    const int* __restrict__ deg, int* __restrict__ rowptr,
    int* __restrict__ cursor, int N)
{
  __shared__ int wtot[16];
  __shared__ int chunk_total_s;
  const int tid = threadIdx.x, lane = tid & 63, wid = tid >> 6;
  int running = 0;
  for (int base = 0; base < N; base += 4096) {
    int i0 = base + tid * 4;
    int d0 = 0, d1 = 0, d2 = 0, d3 = 0;
    if (i0 < N) {
      if (i0 + 3 < N) { int4 t = *(const int4*)(deg + i0); d0 = t.x; d1 = t.y; d2 = t.z; d3 = t.w; }
      else { d0 = deg[i0]; if (i0+1 < N) d1 = deg[i0+1]; if (i0+2 < N) d2 = deg[i0+2]; }
    }
    int tsum = d0 + d1 + d2 + d3;
    int incl = tsum;
    #pragma unroll
    for (int o = 1; o < 64; o <<= 1) {
      int t = __shfl_up(incl, o);
      if (lane >= o) incl += t;
    }
    if (lane == 63) wtot[wid] = incl;
    __syncthreads();
    if (wid == 0 && lane < 16) {
      int t = wtot[lane];
      int inc = t;
      #pragma unroll
      for (int o = 1; o < 16; o <<= 1) {
        int u = __shfl_up(inc, o);
        if (lane >= o) inc += u;
      }
      wtot[lane] = inc - t;
      if (lane == 15) chunk_total_s = inc;
    }
    __syncthreads();
    int excl = running + wtot[wid] + (incl - tsum);
    if (i0 < N) {
      int e1 = excl + d0, e2 = e1 + d1, e3 = e2 + d2;
      if (i0 + 3 < N) {
        *(int4*)(rowptr + i0) = make_int4(excl, e1, e2, e3);
        *(int4*)(cursor + i0) = make_int4(0, 0, 0, 0);
      } else {
        rowptr[i0] = excl; cursor[i0] = 0;
        if (i0+1 < N) { rowptr[i0+1] = e1; cursor[i0+1] = 0; }
        if (i0+2 < N) { rowptr[i0+2] = e2; cursor[i0+2] = 0; }
      }
    }
    running += chunk_total_s;
    __syncthreads();
  }
  if (tid == 0) rowptr[N] = running;
}

__global__ void fill_csr(const int* __restrict__ esrc, const int* __restrict__ edst,
                         int E, int N, const int* __restrict__ rowptr,
                         int* __restrict__ cursor, int* __restrict__ csr)
{
  int e = blockIdx.x * blockDim.x + threadIdx.x;
  int r = blockIdx.y;
  if (e >= E) return;
  int d = r * N + edst[(size_t)r * E + e];
  int pos = atomicAdd(&cursor[d], 1);
  csr[rowptr[d] + pos] = esrc[(size_t)r * E + e];
}

// one wave per (relation, chunk-local dst node): bf16 gather, x4-unrolled ILP
__global__ __launch_bounds__(256) void agg_kernel(
    const ushort* __restrict__ feat, const int* __restrict__ csr,
    const int* __restrict__ rowptr, int N, int c0, int cr, int CH,
    ushort* __restrict__ aggS, ushort* __restrict__ aggM, float* __restrict__ invdeg)
{
  const int wid = threadIdx.x >> 6, lane = threadIdx.x & 63;
  const int node = blockIdx.x * 4 + wid;
  if (node >= cr) return;
  const int g = blockIdx.y * N + c0 + node;
  const int o = blockIdx.y * CH + node;
  const int start = rowptr[g], end = rowptr[g + 1];
  const int j = lane * 4;
  float s0 = 0.f, s1 = 0.f, s2 = 0.f, s3 = 0.f;
  float m0 = -INFINITY, m1 = -INFINITY, m2 = -INFINITY, m3 = -INFINITY;
  int e = start;
  for (; e + 4 <= end; e += 4) {
    int sa = csr[e], sb = csr[e+1], sc = csr[e+2], sd = csr[e+3];
    uint2 va = *(const uint2*)(feat + (size_t)sa * 256 + j);
    uint2 vb = *(const uint2*)(feat + (size_t)sb * 256 + j);
    uint2 vc = *(const uint2*)(feat + (size_t)sc * 256 + j);
    uint2 vd = *(const uint2*)(feat + (size_t)sd * 256 + j);
    float a0, a1, a2, a3;
    a0 = bf2f(va.x & 0xFFFFu); a1 = bf2f(va.x >> 16); a2 = bf2f(va.y & 0xFFFFu); a3 = bf2f(va.y >> 16);
    s0 += a0; s1 += a1; s2 += a2; s3 += a3;
    m0 = fmaxf(m0, a0); m1 = fmaxf(m1, a1); m2 = fmaxf(m2, a2); m3 = fmaxf(m3, a3);
    a0 = bf2f(vb.x & 0xFFFFu); a1 = bf2f(vb.x >> 16); a2 = bf2f(vb.y & 0xFFFFu); a3 = bf2f(vb.y >> 16);
    s0 += a0; s1 += a1; s2 += a2; s3 += a3;
    m0 = fmaxf(m0, a0); m1 = fmaxf(m1, a1); m2 = fmaxf(m2, a2); m3 = fmaxf(m3, a3);
    a0 = bf2f(vc.x & 0xFFFFu); a1 = bf2f(vc.x >> 16); a2 = bf2f(vc.y & 0xFFFFu); a3 = bf2f(vc.y >> 16);
    s0 += a0; s1 += a1; s2 += a2; s3 += a3;
    m0 = fmaxf(m0, a0); m1 = fmaxf(m1, a1); m2 = fmaxf(m2, a2); m3 = fmaxf(m3, a3);
    a0 = bf2f(vd.x & 0xFFFFu); a1 = bf2f(vd.x >> 16); a2 = bf2f(vd.y & 0xFFFFu); a3 = bf2f(vd.y >> 16);
    s0 += a0; s1 += a1; s2 += a2; s3 += a3;
    m0 = fmaxf(m0, a0); m1 = fmaxf(m1, a1); m2 = fmaxf(m2, a2); m3 = fmaxf(m3, a3);
  }
  for (; e < end; ++e) {
    int src = csr[e];
    uint2 v = *(const uint2*)(feat + (size_t)src * 256 + j);
    float a0 = bf2f(v.x & 0xFFFFu), a1 = bf2f(v.x >> 16);
    float a2 = bf2f(v.y & 0xFFFFu), a3 = bf2f(v.y >> 16);
    s0 += a0; s1 += a1; s2 += a2; s3 += a3;
    m0 = fmaxf(m0, a0); m1 = fmaxf(m1, a1); m2 = fmaxf(m2, a2); m3 = fmaxf(m3, a3);
  }
  if (end == start) { m0 = m1 = m2 = m3 = 0.f; }
  uint2 ps; ps.x = pack2(s0, s1); ps.y = pack2(s2, s3);
  *(uint2*)(aggS + (size_t)o * 256 + j) = ps;
  uint2 pm; pm.x = pack2(m0, m1); pm.y = pack2(m2, m3);
  *(uint2*)(aggM + (size_t)o * 256 + j) = pm;
  if (lane == 0) invdeg[o] = 1.f / fmaxf((float)(end - start), 1.f);
}

// ---------------- combine ----------------
__global__ void beta_kernel(const float* __restrict__ wsum, float invN, float* __restrict__ beta) {
  float w0 = wsum[0] * invN, w1 = wsum[1] * invN, w2 = wsum[2] * invN;
  float m  = fmaxf(w0, fmaxf(w1, w2));
  float e0 = expf(w0 - m), e1 = expf(w1 - m), e2 = expf(w2 - m);
  float s  = e0 + e1 + e2;
  beta[0] = e0 / s; beta[1] = e1 / s; beta[2] = e2 / s;
}

// feat1 = bf16[relu(sum_r beta[r]*z1[r]) | tss[nid] | rs[nid]]
__global__ __launch_bounds__(256) void combine1_kernel(
    const float* __restrict__ z1, const float* __restrict__ beta,
    const float* __restrict__ tss, const float* __restrict__ rs,
    const int* __restrict__ nid, int N, ushort* __restrict__ feat1)
{
  int n = blockIdx.x, t = threadIdx.x;
  size_t NH = (size_t)N * 128;
  if (t < 128) {
    float v = beta[0] * z1[(size_t)n*128 + t] + beta[1] * z1[NH + (size_t)n*128 + t]
            + beta[2] * z1[2*NH + (size_t)n*128 + t];
    feat1[(size_t)n*256 + t] = f2bf(fmaxf(v, 0.f));
  } else {
    int j = t - 128;
    int id = nid[n];
    float v = (j < 64) ? tss[(size_t)id*64 + j] : rs[(size_t)id*64 + j - 64];
    feat1[(size_t)n*256 + t] = f2bf(v);
  }
}

__global__ __launch_bounds__(128) void combine2_pred(
    const float* __restrict__ z2, const float* __restrict__ beta, int N,
    const float* __restrict__ pw, const float* __restrict__ pb, float* __restrict__ out)
{
  int n = blockIdx.x, t = threadIdx.x;
  size_t NH = (size_t)N * 128;
  float h = beta[0] * z2[(size_t)n*128 + t] + beta[1] * z2[NH + (size_t)n*128 + t]
          + beta[2] * z2[2*NH + (size_t)n*128 + t];
  float p = h * pw[t];
  #pragma unroll
  for (int o = 32; o > 0; o >>= 1) p += __shfl_down(p, o);
  __shared__ float red[2];
  if ((t & 63) == 0) red[t >> 6] = p;
  __syncthreads();
  if (t == 0) {
    float v = red[0] + red[1] + pb[0];
    out[n] = 1.f / (1.f + expf(-v));
  }
}

extern "C" void kernel_launch(void* const* d_in, const int* in_sizes, int n_in,
                              void* d_out, int out_size, void* d_ws, size_t ws_size,
                              hipStream_t stream)
{
  const float* x_user  = (const float*)d_in[0];
  const float* tss     = (const float*)d_in[1];
  const float* rs      = (const float*)d_in[2];
  const int* src_nid0  = (const int*)d_in[3];
  const int* src_nid1  = (const int*)d_in[4];
  const int* e0_src    = (const int*)d_in[5];
  const int* e0_dst    = (const int*)d_in[6];
  const int* e1_src    = (const int*)d_in[7];
  const int* e1_dst    = (const int*)d_in[8];
  const float* embed_w = (const float*)d_in[9];
  const float* embed_b = (const float*)d_in[10];
  const float* l1w[3]  = {(const float*)d_in[11], (const float*)d_in[13], (const float*)d_in[15]};
  const float* l1b[3]  = {(const float*)d_in[12], (const float*)d_in[14], (const float*)d_in[16]};
  const float* l2w[3]  = {(const float*)d_in[17], (const float*)d_in[19], (const float*)d_in[21]};
  const float* l2b[3]  = {(const float*)d_in[18], (const float*)d_in[20], (const float*)d_in[22]};
  const float* attn_w1 = (const float*)d_in[23];
  const float* attn_b1 = (const float*)d_in[24];
  const float* attn_w2 = (const float*)d_in[25];
  const float* pred_w  = (const float*)d_in[26];
  const float* pred_b  = (const float*)d_in[27];
  float* out = (float*)d_out;

  const int N0 = in_sizes[0] / 128;
  const int N1 = in_sizes[4];
  const int N2 = out_size;
  const int E0 = in_sizes[5] / 3;
  const int E1 = in_sizes[7] / 3;

  char* wp = (char*)d_ws;
  auto walloc = [&](size_t bytes) {
    char* p = wp; wp += (bytes + 255) & ~(size_t)255; return p;
  };
  // Fixed allocations (~117 MB)
  ushort* feat0  = (ushort*)walloc((size_t)N0 * 256 * 2);      // bf16
  ushort* inp    = (ushort*)walloc((size_t)3 * N1 * 256 * 2);  // bf16
  float*  z      = (float*)walloc((size_t)3 * N1 * 128 * 4);   // fp32
  ushort* wt_emb = (ushort*)walloc((size_t)128 * 128 * 2);
  ushort* wt_attn = (ushort*)walloc((size_t)128 * 128 * 2);
  ushort* wt_fc1[2], *wt_fc2[2], *wt_fc3[2];
  for (int l = 0; l < 2; ++l) {
    wt_fc1[l] = (ushort*)walloc((size_t)3 * 256 * 128 * 2);
    wt_fc2[l] = (ushort*)walloc((size_t)3 * 768 * 128 * 2);
    wt_fc3[l] = (ushort*)walloc((size_t)3 * 256 * 128 * 2);
  }
  int*   degcnt = (int*)walloc((size_t)3 * N1 * 4);
  int*   rowptr = (int*)walloc((size_t)(3 * N1 + 1) * 4);
  int*   csr    = (int*)walloc((size_t)3 * E0 * 4);
  float* small  = (float*)walloc(256);
  float* wsum = small;
  float* beta = small + 4;
  ushort* feat1 = feat0;

  // Adaptive agg chunk size (bf16 agg buffers)
  size_t used = (size_t)(wp - (char*)d_ws);
  size_t avail = (ws_size > used + 65536) ? (ws_size - used - 65536) : 0;
  const size_t per_row = (size_t)3 * (2 * 256 * 2 + 4 + 64);
  int CH = (int)(avail / per_row);
  if (CH > N1) CH = N1;
  if (CH < 1024) CH = 1024;
  ushort* aggS   = (ushort*)walloc((size_t)3 * CH * 256 * 2);
  ushort* aggM   = (ushort*)walloc((size_t)3 * CH * 256 * 2);
  float*  invdeg = (float*)walloc((size_t)3 * CH * 4);
  (void)n_in;

  // ---- weight prep: 8 tensors in one launch ----
  {
    PrepAll P;
    P.src[0] = embed_w;  P.dst[0] = wt_emb;    P.K[0] = 128; P.total[0] = 128 * 128;
    P.src[1] = attn_w1;  P.dst[1] = wt_attn;   P.K[1] = 128; P.total[1] = 128 * 128;
    P.src[2] = l1w[0];   P.dst[2] = wt_fc1[0]; P.K[2] = 256; P.total[2] = 3 * 256 * 128;
    P.src[3] = l1w[1];   P.dst[3] = wt_fc2[0]; P.K[3] = 768; P.total[3] = 3 * 768 * 128;
    P.src[4] = l1w[2];   P.dst[4] = wt_fc3[0]; P.K[4] = 256; P.total[4] = 3 * 256 * 128;
    P.src[5] = l2w[0];   P.dst[5] = wt_fc1[1]; P.K[5] = 256; P.total[5] = 3 * 256 * 128;
    P.src[6] = l2w[1];   P.dst[6] = wt_fc2[1]; P.K[6] = 768; P.total[6] = 3 * 768 * 128;
    P.src[7] = l2w[2];   P.dst[7] = wt_fc3[1]; P.K[7] = 256; P.total[7] = 3 * 256 * 128;
    prep_all<<<dim3((3 * 768 * 128 + 255) / 256, 1, 8), 256, 0, stream>>>(P);
  }

  GemmDesc dz = {};
  dz.K = 256;   // benign default for the unused descriptor slot

  // ---- feat0 = bf16[x@embed | tss | rs] (gather fused into epilogue) ----
  {
    GemmDesc d{};
    d.A = x_user; d.lda = 128; d.aStride = 0; d.aKind = 0;
    d.Wt = wt_emb; d.wStride = 0; d.bias = embed_b; d.biasStride = 0;
    d.C = feat0; d.ldc = 256; d.cStride = 0; d.cKind = 1;
    d.M = N0; d.K = 128; d.relu = 0;
    d.aggM = aggM; d.aggS = aggS; d.invdeg = invdeg; d.aggStride = 0; d.invStride = 0;
    d.gnid = src_nid0; d.gtss = tss; d.grs = rs;
    gemm_mfma<<<dim3((N0 + 63) / 64, 1, 1), 256, 0, stream>>>(d, dz);
  }

  // ---- two conv layers ----
  for (int layer = 0; layer < 2; ++layer) {
    const ushort* featS = layer ? feat1 : feat0;
    int Nd = layer ? N2 : N1;
    int E  = layer ? E1 : E0;
    const int* es = layer ? e1_src : e0_src;
    const int* ed = layer ? e1_dst : e0_dst;
    const float* const* lb = layer ? l2b : l1b;

    // CSR build for all 3 relations
    hipMemsetAsync(degcnt, 0, (size_t)3 * Nd * 4, stream);
    count_deg<<<dim3((E + 255) / 256, 3), 256, 0, stream>>>(ed, E, Nd, degcnt);
    scan_kernel<<<1, 1024, 0, stream>>>(degcnt, rowptr, degcnt, 3 * Nd);
    fill_csr<<<dim3((E + 255) / 256, 3), 256, 0, stream>>>(es, ed, E, Nd, rowptr, degcnt, csr);

    // chunked: agg -> fused fc2 (z=0, K=768 virtual) + fc1 (z=1, K=256)
    for (int c0 = 0; c0 < Nd; c0 += CH) {
      int cr = (Nd - c0 < CH) ? (Nd - c0) : CH;
      agg_kernel<<<dim3((cr + 3) / 4, 3), 256, 0, stream>>>(
          featS, csr, rowptr, Nd, c0, cr, CH, aggS, aggM, invdeg);
      GemmDesc d2{};
      d2.A = nullptr; d2.lda = 0; d2.aStride = 0; d2.aKind = 2;
      d2.Wt = wt_fc2[layer]; d2.wStride = (size_t)768 * 128; d2.bias = lb[1]; d2.biasStride = 128;
      d2.C = inp + (size_t)c0 * 256; d2.ldc = 256; d2.cStride = (size_t)Nd * 256; d2.cKind = 1;
      d2.M = cr; d2.K = 768; d2.relu = 1;
      d2.aggM = aggM; d2.aggS = aggS; d2.invdeg = invdeg;
      d2.aggStride = (size_t)CH * 256; d2.invStride = CH;
      GemmDesc d1{};
      d1.A = featS + (size_t)c0 * 256; d1.lda = 256; d1.aStride = 0; d1.aKind = 1;
      d1.Wt = wt_fc1[layer]; d1.wStride = (size_t)256 * 128; d1.bias = lb[0]; d1.biasStride = 128;
      d1.C = inp + 128 + (size_t)c0 * 256; d1.ldc = 256; d1.cStride = (size_t)Nd * 256; d1.cKind = 1;
      d1.M = cr; d1.K = 256; d1.relu = 1;
      d1.aggM = aggM; d1.aggS = aggS; d1.invdeg = invdeg; d1.aggStride = 0; d1.invStride = 0;
      gemm_mfma<<<dim3((cr + 63) / 64, 3, 2), 256, 0, stream>>>(d2, d1);
    }
    // fc3 -> z (fp32)
    {
      GemmDesc d3{};
      d3.A = inp; d3.lda = 256; d3.aStride = (size_t)Nd * 256; d3.aKind = 1;
      d3.Wt = wt_fc3[layer]; d3.wStride = (size_t)256 * 128; d3.bias = lb[2]; d3.biasStride = 128;
      d3.C = z; d3.ldc = 128; d3.cStride = (size_t)Nd * 128; d3.cKind = 0;
      d3.M = Nd; d3.K = 256; d3.relu = 0;
      d3.aggM = aggM; d3.aggS = aggS; d3.invdeg = invdeg; d3.aggStride = 0; d3.invStride = 0;
      gemm_mfma<<<dim3((Nd + 63) / 64, 3, 1), 256, 0, stream>>>(d3, dz);
    }

    hipMemsetAsync(wsum, 0, 3 * sizeof(float), stream);
    attn_mfma<<<dim3((Nd + 63) / 64, 3), 256, 0, stream>>>(z, wt_attn, attn_b1, attn_w2, Nd, wsum);
    beta_kernel<<<1, 1, 0, stream>>>(wsum, 1.0f / (float)Nd, beta);

    if (layer == 0) {
      combine1_kernel<<<N1, 256, 0, stream>>>(z, beta, tss, rs, src_nid1, N1, feat1);
    } else {
      combine2_pred<<<N2, 128, 0, stream>>>(z, beta, N2, pred_w, pred_b, out);
    }
  }
}

// Round 5
// 522.450 us; speedup vs baseline: 1.0548x; 1.0548x over previous
//
#include <hip/hip_runtime.h>
#include <math.h>

// ---------------------------------------------------------------------------
// IG_RGCN forward on MI355X. Round 9: fuse attention into fc3 + parallel scan.
//  - fc3_attn: fc3 GEMM keeps z in registers, writes fp32 z, transposes bf16
//    z into XOR-swizzled LDS, runs the 128x128 attn GEMM + tanh*w2 reduce in
//    the same kernel (1 atomicAdd/block). Removes attn_mfma dispatches and
//    2x(30+6)MB of z re-reads.
//  - scan_kernel: per-relation (grid.y=3) -> 3x fewer serial iterations of
//    the single-block scan; rowptr now [r][(N+1)], csr offset r*E.
//  - embed/fc1/fc2 GEMM core unchanged from round 8 (proven neutral-or-better,
//    0 bank conflicts); agg/combine unchanged.
// ---------------------------------------------------------------------------

typedef short s16x8 __attribute__((ext_vector_type(8)));
typedef float f32x4 __attribute__((ext_vector_type(4)));

__device__ __forceinline__ ushort f2bf(float f) {
  unsigned u = __float_as_uint(f);
  return (ushort)((u + 0x7FFFu + ((u >> 16) & 1u)) >> 16);
}
__device__ __forceinline__ float bf2f(unsigned hbits) {
  return __uint_as_float(hbits << 16);
}
__device__ __forceinline__ unsigned pack2(float lo, float hi) {
  return (unsigned)f2bf(lo) | ((unsigned)f2bf(hi) << 16);
}

// ---- one-shot weight prep: 8 tensors, W[r][K][128] fp32 -> Wt[r][128][K] bf16
struct PrepAll {
  const float* src[8];
  ushort* dst[8];
  int K[8];
  int total[8];   // R*K*128
};

__global__ __launch_bounds__(256) void prep_all(PrepAll P)
{
  int t = blockIdx.z;
  int off = blockIdx.x * 256 + threadIdx.x;
  if (off >= P.total[t]) return;
  int K = P.K[t];
  int k = off % K;
  int n = (off / K) & 127;
  int r = off / (K * 128);
  P.dst[t][off] = f2bf(P.src[t][((size_t)r * K + k) * 128 + n]);
}

struct GemmDesc {
  const void* A; int lda; size_t aStride; int aKind;   // 0 fp32, 1 bf16, 2 virtual agg
  const ushort* Wt; size_t wStride;                    // [128][K] bf16 per relation
  const float* bias; int biasStride;
  void* C; int ldc; size_t cStride; int cKind;         // 0 fp32, 1 bf16
  int M, K, relu;
  const ushort* aggM; const ushort* aggS; const float* invdeg;
  size_t aggStride; int invStride;
  // optional fused gather (embed only): fill C cols 128..255 with bf16(tss|rs)[nid]
  const int* gnid; const float* gtss; const float* grs;
};

// Load one A fragment (16 bf16 k-values for this lane's row) at k-offset k0.
template<int AKIND>
__device__ __forceinline__ uint4 loadA(const void* Ab, const ushort* AgM,
                                       const ushort* AgS, int lda, int row,
                                       bool rowOK, int k0, int quad, float idg)
{
  uint4 pk = make_uint4(0u, 0u, 0u, 0u);
  if (rowOK) {
    if constexpr (AKIND == 1) {
      pk = *(const uint4*)((const ushort*)Ab + (size_t)row * lda + k0 + quad * 8);
    } else if constexpr (AKIND == 0) {
      const float* A32 = (const float*)Ab;
      float4 fa = *(const float4*)(A32 + (size_t)row * lda + k0 + quad * 8);
      float4 fb = *(const float4*)(A32 + (size_t)row * lda + k0 + quad * 8 + 4);
      pk.x = pack2(fa.x, fa.y); pk.y = pack2(fa.z, fa.w);
      pk.z = pack2(fb.x, fb.y); pk.w = pack2(fb.z, fb.w);
    } else {                               // virtual [mx | sum*invdeg | sum]
      int seg = k0 >> 8;
      int jj  = (k0 & 255) + quad * 8;
      const ushort* Ag = (seg == 0) ? AgM : AgS;
      pk = *(const uint4*)(Ag + (size_t)row * 256 + jj);
      if (seg == 1) {
        pk.x = pack2(bf2f(pk.x & 0xFFFFu) * idg, bf2f(pk.x >> 16) * idg);
        pk.y = pack2(bf2f(pk.y & 0xFFFFu) * idg, bf2f(pk.y >> 16) * idg);
        pk.z = pack2(bf2f(pk.z & 0xFFFFu) * idg, bf2f(pk.z >> 16) * idg);
        pk.w = pack2(bf2f(pk.w & 0xFFFFu) * idg, bf2f(pk.w >> 16) * idg);
      }
    }
  }
  return pk;
}

// Core: C[M,128] = act(A[M,K] @ W + b). 64 rows/block, 16 rows/wave.
// B staged per 64-K chunk in MFMA-fragment order (16 KB LDS):
// Bs[(ks*8+j)*64+lane] <- Wt[col=j*16+(lane&15)][k=c*64+ks*32+(lane>>4)*8..+8]
template<int K, int AKIND>
__device__ __forceinline__ void gemm_core(const GemmDesc& d, int r, ushort* Bs)
{
  constexpr int NC = K / 64;     // 64-K staging chunks
  constexpr int NF = K / 32;     // A fragments per row

  const int tid = threadIdx.x;
  const int wave = tid >> 6, lane = tid & 63;
  const int m16 = lane & 15, quad = lane >> 4;
  const int rowBase = blockIdx.x * 64;
  const int row = rowBase + wave * 16 + m16;
  const bool rowOK = row < d.M;
  const ushort* Wt = d.Wt + (size_t)r * d.wStride;

  const void* Ab = (const char*)d.A +
      (size_t)r * d.aStride * (AKIND == 0 ? sizeof(float) : sizeof(ushort));
  const ushort* AgM = d.aggM + (size_t)r * d.aggStride;
  const ushort* AgS = d.aggS + (size_t)r * d.aggStride;

  float idg = 1.f;
  if (AKIND == 2 && rowOK) idg = d.invdeg[(size_t)r * d.invStride + row];

  f32x4 acc[8];
  #pragma unroll
  for (int j = 0; j < 8; ++j)
    #pragma unroll
    for (int p = 0; p < 4; ++p) acc[j][p] = 0.f;

  // A prefetch: all fragments for K<=256 (static-indexed -> registers)
  uint4 pkAll[(K <= 256) ? NF : 2];
  if constexpr (K <= 256) {
    #pragma unroll
    for (int f = 0; f < NF; ++f)
      pkAll[f] = loadA<AKIND>(Ab, AgM, AgS, d.lda, row, rowOK, f * 32, quad, idg);
  }

  #pragma unroll
  for (int c = 0; c < NC; ++c) {
    if constexpr (K > 256) {   // issue this chunk's A before barriers
      pkAll[0] = loadA<AKIND>(Ab, AgM, AgS, d.lda, row, rowOK, c * 64,      quad, idg);
      pkAll[1] = loadA<AKIND>(Ab, AgM, AgS, d.lda, row, rowOK, c * 64 + 32, quad, idg);
    }
    if (c) __syncthreads();                 // waves done reading prev chunk
    #pragma unroll
    for (int i = 0; i < 4; ++i) {           // stage 1024 frags (16 KB)
      int q = tid + 256 * i;
      int col = ((q >> 6) & 7) * 16 + (q & 15);
      int kk  = c * 64 + ((q >> 9) & 1) * 32 + ((q >> 4) & 3) * 8;
      *(uint4*)&Bs[q * 8] = *(const uint4*)(Wt + (size_t)col * K + kk);
    }
    __syncthreads();

    #pragma unroll
    for (int ks = 0; ks < 2; ++ks) {
      uint4 pk = (K <= 256) ? pkAll[c * 2 + ks] : pkAll[ks];
      s16x8 af = *(s16x8*)&pk;
      #pragma unroll
      for (int j = 0; j < 8; ++j) {
        s16x8 bf = *(const s16x8*)&Bs[((ks * 8 + j) * 64 + lane) * 8];
        acc[j] = __builtin_amdgcn_mfma_f32_16x16x32_bf16(af, bf, acc[j], 0, 0, 0);
      }
    }
  }

  const float* bias = d.bias + (size_t)r * d.biasStride;
  float bcol[8];
  #pragma unroll
  for (int j = 0; j < 8; ++j) bcol[j] = bias[j * 16 + m16];

  #pragma unroll
  for (int p = 0; p < 4; ++p) {
    int grow = rowBase + wave * 16 + quad * 4 + p;
    if (grow >= d.M) continue;
    if (d.cKind == 0) {
      float* Crow = (float*)d.C + (size_t)r * d.cStride + (size_t)grow * d.ldc;
      #pragma unroll
      for (int j = 0; j < 8; ++j) {
        float v = acc[j][p] + bcol[j];
        if (d.relu) v = fmaxf(v, 0.f);
        Crow[j * 16 + m16] = v;
      }
    } else {
      ushort* Crow = (ushort*)d.C + (size_t)r * d.cStride + (size_t)grow * d.ldc;
      #pragma unroll
      for (int j = 0; j < 8; ++j) {
        float v = acc[j][p] + bcol[j];
        if (d.relu) v = fmaxf(v, 0.f);
        Crow[j * 16 + m16] = f2bf(v);
      }
    }
  }

  // fused gather (embed only): C cols 128..255 <- bf16(tss[nid] | rs[nid])
  if constexpr (K == 128) {
    if (d.gnid) {
      #pragma unroll
      for (int i = 0; i < 8; ++i) {
        int q = tid + 256 * i;            // 2048 tasks: 64 rows x 32 chunks
        int grow = rowBase + (q >> 5);
        int c = q & 31;
        if (grow >= d.M) continue;
        int id = d.gnid[grow];
        float4 v = (c < 16) ? *(const float4*)(d.gtss + (size_t)id * 64 + c * 4)
                            : *(const float4*)(d.grs  + (size_t)id * 64 + (c - 16) * 4);
        uint2 g; g.x = pack2(v.x, v.y); g.y = pack2(v.z, v.w);
        *(uint2*)((ushort*)d.C + (size_t)grow * d.ldc + 128 + c * 4) = g;
      }
    }
  }
}

__global__ __launch_bounds__(256, 4) void gemm_mfma(GemmDesc d0, GemmDesc d1)
{
  __shared__ __align__(16) ushort Bs[1024 * 8];   // 16 KB
  const GemmDesc& d = blockIdx.z ? d1 : d0;
  const int r = blockIdx.y;
  if (d.K == 128)      gemm_core<128, 0>(d, r, Bs);
  else if (d.K == 256) gemm_core<256, 1>(d, r, Bs);
  else                 gemm_core<768, 2>(d, r, Bs);
}

// ---- fc3 + semantic attention fused.
// Phase 1: z = inp @ W3 + b3 (K=256, bf16 A prefetched; identical structure
//          to gemm_core<256,1> with fp32 C kept in registers).
// Phase 2: bf16(z) -> XOR-swizzled LDS tile; attn = zb @ w1t (K=128, 2 chunks);
//          wsum[r] += sum tanh(attn + b1) * w2.
__global__ __launch_bounds__(256) void fc3_attn(
    const ushort* __restrict__ inp, size_t aStride,
    const ushort* __restrict__ wt3, size_t wStride,
    const float* __restrict__ b3,
    float* __restrict__ z, size_t zStride, int M,
    const ushort* __restrict__ w1t, const float* __restrict__ b1,
    const float* __restrict__ w2, float* __restrict__ wsum)
{
  __shared__ __align__(16) ushort Zs[64 * 128];   // 16 KB bf16 z tile (swizzled)
  __shared__ __align__(16) ushort Ws[1024 * 8];   // 16 KB B staging

  const int tid = threadIdx.x;
  const int wave = tid >> 6, lane = tid & 63;
  const int m16 = lane & 15, quad = lane >> 4;
  const int r = blockIdx.y;
  const int rowBase = blockIdx.x * 64;
  const int row = rowBase + wave * 16 + m16;
  const bool rowOK = row < M;

  const ushort* A  = inp + (size_t)r * aStride;
  const ushort* Wt = wt3 + (size_t)r * wStride;

  f32x4 acc[8];
  #pragma unroll
  for (int j = 0; j < 8; ++j)
    #pragma unroll
    for (int p = 0; p < 4; ++p) acc[j][p] = 0.f;

  uint4 pkAll[8];
  #pragma unroll
  for (int f = 0; f < 8; ++f) {
    uint4 pk = make_uint4(0u, 0u, 0u, 0u);
    if (rowOK) pk = *(const uint4*)(A + (size_t)row * 256 + f * 32 + quad * 8);
    pkAll[f] = pk;
  }

  #pragma unroll
  for (int c = 0; c < 4; ++c) {                 // K = 256: 4 chunks of 64
    if (c) __syncthreads();
    #pragma unroll
    for (int i = 0; i < 4; ++i) {
      int q = tid + 256 * i;
      int col = ((q >> 6) & 7) * 16 + (q & 15);
      int kk  = c * 64 + ((q >> 9) & 1) * 32 + ((q >> 4) & 3) * 8;
      *(uint4*)&Ws[q * 8] = *(const uint4*)(Wt + (size_t)col * 256 + kk);
    }
    __syncthreads();
    #pragma unroll
    for (int ks = 0; ks < 2; ++ks) {
      s16x8 af = *(s16x8*)&pkAll[c * 2 + ks];
      #pragma unroll
      for (int j = 0; j < 8; ++j) {
        s16x8 bf = *(const s16x8*)&Ws[((ks * 8 + j) * 64 + lane) * 8];
        acc[j] = __builtin_amdgcn_mfma_f32_16x16x32_bf16(af, bf, acc[j], 0, 0, 0);
      }
    }
  }

  const float* bias = b3 + (size_t)r * 128;
  float bcol[8];
  #pragma unroll
  for (int j = 0; j < 8; ++j) bcol[j] = bias[j * 16 + m16];

  // z write (fp32) + bf16 z into swizzled LDS (zeros for OOB rows)
  #pragma unroll
  for (int p = 0; p < 4; ++p) {
    int lrow = wave * 16 + quad * 4 + p;
    int grow = rowBase + lrow;
    bool ok = grow < M;
    float* Zr = z + (size_t)r * zStride + (size_t)grow * 128;
    #pragma unroll
    for (int j = 0; j < 8; ++j) {
      float v = ok ? acc[j][p] + bcol[j] : 0.f;
      if (ok) Zr[j * 16 + m16] = v;
      int byte = lrow * 256 + (j * 16 + m16) * 2;
      byte ^= (lrow & 7) << 4;
      *(ushort*)((char*)Zs + byte) = f2bf(v);
    }
  }

  // attention GEMM: acc2 = zb @ w1t  (A rows from swizzled Zs)
  f32x4 acc2[8];
  #pragma unroll
  for (int j = 0; j < 8; ++j)
    #pragma unroll
    for (int p = 0; p < 4; ++p) acc2[j][p] = 0.f;

  const int arow = wave * 16 + m16;
  #pragma unroll
  for (int c = 0; c < 2; ++c) {
    __syncthreads();      // phase-1 Ws reads + all Zs writes complete
    #pragma unroll
    for (int i = 0; i < 4; ++i) {
      int q = tid + 256 * i;
      int col = ((q >> 6) & 7) * 16 + (q & 15);
      int kk  = c * 64 + ((q >> 9) & 1) * 32 + ((q >> 4) & 3) * 8;
      *(uint4*)&Ws[q * 8] = *(const uint4*)(w1t + (size_t)col * 128 + kk);
    }
    __syncthreads();
    #pragma unroll
    for (int ks = 0; ks < 2; ++ks) {
      int kk = c * 64 + ks * 32 + quad * 8;
      int byte = arow * 256 + kk * 2;
      byte ^= (arow & 7) << 4;
      s16x8 af = *(const s16x8*)((const char*)Zs + byte);
      #pragma unroll
      for (int j = 0; j < 8; ++j) {
        s16x8 bf = *(const s16x8*)&Ws[((ks * 8 + j) * 64 + lane) * 8];
        acc2[j] = __builtin_amdgcn_mfma_f32_16x16x32_bf16(af, bf, acc2[j], 0, 0, 0);
      }
    }
  }

  float b1c[8], w2c[8];
  #pragma unroll
  for (int j = 0; j < 8; ++j) { b1c[j] = b1[j * 16 + m16]; w2c[j] = w2[j * 16 + m16]; }

  float local = 0.f;
  #pragma unroll
  for (int p = 0; p < 4; ++p) {
    int grow = rowBase + wave * 16 + quad * 4 + p;
    if (grow >= M) continue;
    #pragma unroll
    for (int j = 0; j < 8; ++j)
      local += tanhf(acc2[j][p] + b1c[j]) * w2c[j];
  }
  #pragma unroll
  for (int o = 32; o > 0; o >>= 1) local += __shfl_down(local, o);
  __shared__ float red[4];
  if (lane == 0) red[wave] = local;
  __syncthreads();
  if (tid == 0) atomicAdd(&wsum[r], red[0] + red[1] + red[2] + red[3]);
}

// ---------------- CSR build (batched over R=3 relations) ----------------
__global__ void count_deg(const int* __restrict__ edst, int E, int N, int* __restrict__ deg)
{
  int e = blockIdx.x * blockDim.x + threadIdx.x;
  int r = blockIdx.y;
  if (e < E) atomicAdd(&deg[r * N + edst[(size_t)r * E + e]], 1);
}

// per-relation exclusive scan (blockIdx.y = r), 4096 elems/iter.
// rowptr layout: [r][(N+1)]; cursor (aliases deg) zeroed.
__global__ __launch_bounds__(1024) void scan_kernel(
    const int* __restrict__ deg, int* __restrict__ rowptr,
    int* __restrict__ cursor, int N)
{
  const int r = blockIdx.y;
  const int* dg = deg + (size_t)r * N;
  int* rp  = rowptr + (size_t)r * (N + 1);
  int* cur = cursor + (size_t)r * N;

  __shared__ int wtot[16];
  __shared__ int chunk_total_s;
  const int tid = threadIdx.x, lane = tid & 63, wid = tid >> 6;
  int running = 0;
  for (int base = 0; base < N; base += 4096) {
    int i0 = base + tid * 4;
    int d0 = 0, d1 = 0, d2 = 0, d3 = 0;
    if (i0 < N) {
      if (i0 + 3 < N) { int4 t = *(const int4*)(dg + i0); d0 = t.x; d1 = t.y; d2 = t.z; d3 = t.w; }
      else { d0 = dg[i0]; if (i0+1 < N) d1 = dg[i0+1]; if (i0+2 < N) d2 = dg[i0+2]; }
    }
    int tsum = d0 + d1 + d2 + d3;
    int incl = tsum;
    #pragma unroll
    for (int o = 1; o < 64; o <<= 1) {
      int t = __shfl_up(incl, o);
      if (lane >= o) incl += t;
    }
    if (lane == 63) wtot[wid] = incl;
    __syncthreads();
    if (wid == 0 && lane < 16) {
      int t = wtot[lane];
      int inc = t;
      #pragma unroll
      for (int o = 1; o < 16; o <<= 1) {
        int u = __shfl_up(inc, o);
        if (lane >= o) inc += u;
      }
      wtot[lane] = inc - t;
      if (lane == 15) chunk_total_s = inc;
    }
    __syncthreads();
    int excl = running + wtot[wid] + (incl - tsum);
    if (i0 < N) {
      int e1 = excl + d0, e2 = e1 + d1, e3 = e2 + d2;
      if (i0 + 3 < N) {
        *(int4*)(rp + i0) = make_int4(excl, e1, e2, e3);
        *(int4*)(cur + i0) = make_int4(0, 0, 0, 0);
      } else {
        rp[i0] = excl; cur[i0] = 0;
        if (i0+1 < N) { rp[i0+1] = e1; cur[i0+1] = 0; }
        if (i0+2 < N) { rp[i0+2] = e2; cur[i0+2] = 0; }
      }
    }
    running += chunk_total_s;
    __syncthreads();
  }
  if (tid == 0) rp[N] = running;
}

__global__ void fill_csr(const int* __restrict__ esrc, const int* __restrict__ edst,
                         int E, int N, const int* __restrict__ rowptr,
                         int* __restrict__ cursor, int* __restrict__ csr)
{
  int e = blockIdx.x * blockDim.x + threadIdx.x;
  int r = blockIdx.y;
  if (e >= E) return;
  int dn = edst[(size_t)r * E + e];
  int pos = atomicAdd(&cursor[r * N + dn], 1);
  csr[(size_t)r * E + rowptr[(size_t)r * (N + 1) + dn] + pos] = esrc[(size_t)r * E + e];
}

// one wave per (relation, chunk-local dst node): bf16 gather, x4-unrolled ILP
__global__ __launch_bounds__(256) void agg_kernel(
    const ushort* __restrict__ feat, const int* __restrict__ csr,
    const int* __restrict__ rowptr, int N, int c0, int cr, int CH, int E,
    ushort* __restrict__ aggS, ushort* __restrict__ aggM, float* __restrict__ invdeg)
{
  const int wid = threadIdx.x >> 6, lane = threadIdx.x & 63;
  const int node = blockIdx.x * 4 + wid;
  if (node >= cr) return;
  const size_t rp = (size_t)blockIdx.y * (N + 1) + c0 + node;
  const int o = blockIdx.y * CH + node;
  const int start = rowptr[rp], end = rowptr[rp + 1];
  const int* ecsr = csr + (size_t)blockIdx.y * E;
  const int j = lane * 4;
  float s0 = 0.f, s1 = 0.f, s2 = 0.f, s3 = 0.f;
  float m0 = -INFINITY, m1 = -INFINITY, m2 = -INFINITY, m3 = -INFINITY;
  int e = start;
  for (; e + 4 <= end; e += 4) {
    int sa = ecsr[e], sb = ecsr[e+1], sc = ecsr[e+2], sd = ecsr[e+3];
    uint2 va = *(const uint2*)(feat + (size_t)sa * 256 + j);
    uint2 vb = *(const uint2*)(feat + (size_t)sb * 256 + j);
    uint2 vc = *(const uint2*)(feat + (size_t)sc * 256 + j);
    uint2 vd = *(const uint2*)(feat + (size_t)sd * 256 + j);
    float a0, a1, a2, a3;
    a0 = bf2f(va.x & 0xFFFFu); a1 = bf2f(va.x >> 16); a2 = bf2f(va.y & 0xFFFFu); a3 = bf2f(va.y >> 16);
    s0 += a0; s1 += a1; s2 += a2; s3 += a3;
    m0 = fmaxf(m0, a0); m1 = fmaxf(m1, a1); m2 = fmaxf(m2, a2); m3 = fmaxf(m3, a3);
    a0 = bf2f(vb.x & 0xFFFFu); a1 = bf2f(vb.x >> 16); a2 = bf2f(vb.y & 0xFFFFu); a3 = bf2f(vb.y >> 16);
    s0 += a0; s1 += a1; s2 += a2; s3 += a3;
    m0 = fmaxf(m0, a0); m1 = fmaxf(m1, a1); m2 = fmaxf(m2, a2); m3 = fmaxf(m3, a3);
    a0 = bf2f(vc.x & 0xFFFFu); a1 = bf2f(vc.x >> 16); a2 = bf2f(vc.y & 0xFFFFu); a3 = bf2f(vc.y >> 16);
    s0 += a0; s1 += a1; s2 += a2; s3 += a3;
    m0 = fmaxf(m0, a0); m1 = fmaxf(m1, a1); m2 = fmaxf(m2, a2); m3 = fmaxf(m3, a3);
    a0 = bf2f(vd.x & 0xFFFFu); a1 = bf2f(vd.x >> 16); a2 = bf2f(vd.y & 0xFFFFu); a3 = bf2f(vd.y >> 16);
    s0 += a0; s1 += a1; s2 += a2; s3 += a3;
    m0 = fmaxf(m0, a0); m1 = fmaxf(m1, a1); m2 = fmaxf(m2, a2); m3 = fmaxf(m3, a3);
  }
  for (; e < end; ++e) {
    int src = ecsr[e];
    uint2 v = *(const uint2*)(feat + (size_t)src * 256 + j);
    float a0 = bf2f(v.x & 0xFFFFu), a1 = bf2f(v.x >> 16);
    float a2 = bf2f(v.y & 0xFFFFu), a3 = bf2f(v.y >> 16);
    s0 += a0; s1 += a1; s2 += a2; s3 += a3;
    m0 = fmaxf(m0, a0); m1 = fmaxf(m1, a1); m2 = fmaxf(m2, a2); m3 = fmaxf(m3, a3);
  }
  if (end == start) { m0 = m1 = m2 = m3 = 0.f; }
  uint2 ps; ps.x = pack2(s0, s1); ps.y = pack2(s2, s3);
  *(uint2*)(aggS + (size_t)o * 256 + j) = ps;
  uint2 pm; pm.x = pack2(m0, m1); pm.y = pack2(m2, m3);
  *(uint2*)(aggM + (size_t)o * 256 + j) = pm;
  if (lane == 0) invdeg[o] = 1.f / fmaxf((float)(end - start), 1.f);
}

// ---------------- combine ----------------
__global__ void beta_kernel(const float* __restrict__ wsum, float invN, float* __restrict__ beta) {
  float w0 = wsum[0] * invN, w1 = wsum[1] * invN, w2 = wsum[2] * invN;
  float m  = fmaxf(w0, fmaxf(w1, w2));
  float e0 = expf(w0 - m), e1 = expf(w1 - m), e2 = expf(w2 - m);
  float s  = e0 + e1 + e2;
  beta[0] = e0 / s; beta[1] = e1 / s; beta[2] = e2 / s;
}

// feat1 = bf16[relu(sum_r beta[r]*z1[r]) | tss[nid] | rs[nid]]
__global__ __launch_bounds__(256) void combine1_kernel(
    const float* __restrict__ z1, const float* __restrict__ beta,
    const float* __restrict__ tss, const float* __restrict__ rs,
    const int* __restrict__ nid, int N, ushort* __restrict__ feat1)
{
  int n = blockIdx.x, t = threadIdx.x;
  size_t NH = (size_t)N * 128;
  if (t < 128) {
    float v = beta[0] * z1[(size_t)n*128 + t] + beta[1] * z1[NH + (size_t)n*128 + t]
            + beta[2] * z1[2*NH + (size_t)n*128 + t];
    feat1[(size_t)n*256 + t] = f2bf(fmaxf(v, 0.f));
  } else {
    int j = t - 128;
    int id = nid[n];
    float v = (j < 64) ? tss[(size_t)id*64 + j] : rs[(size_t)id*64 + j - 64];
    feat1[(size_t)n*256 + t] = f2bf(v);
  }
}

__global__ __launch_bounds__(128) void combine2_pred(
    const float* __restrict__ z2, const float* __restrict__ beta, int N,
    const float* __restrict__ pw, const float* __restrict__ pb, float* __restrict__ out)
{
  int n = blockIdx.x, t = threadIdx.x;
  size_t NH = (size_t)N * 128;
  float h = beta[0] * z2[(size_t)n*128 + t] + beta[1] * z2[NH + (size_t)n*128 + t]
          + beta[2] * z2[2*NH + (size_t)n*128 + t];
  float p = h * pw[t];
  #pragma unroll
  for (int o = 32; o > 0; o >>= 1) p += __shfl_down(p, o);
  __shared__ float red[2];
  if ((t & 63) == 0) red[t >> 6] = p;
  __syncthreads();
  if (t == 0) {
    float v = red[0] + red[1] + pb[0];
    out[n] = 1.f / (1.f + expf(-v));
  }
}

extern "C" void kernel_launch(void* const* d_in, const int* in_sizes, int n_in,
                              void* d_out, int out_size, void* d_ws, size_t ws_size,
                              hipStream_t stream)
{
  const float* x_user  = (const float*)d_in[0];
  const float* tss     = (const float*)d_in[1];
  const float* rs      = (const float*)d_in[2];
  const int* src_nid0  = (const int*)d_in[3];
  const int* src_nid1  = (const int*)d_in[4];
  const int* e0_src    = (const int*)d_in[5];
  const int* e0_dst    = (const int*)d_in[6];
  const int* e1_src    = (const int*)d_in[7];
  const int* e1_dst    = (const int*)d_in[8];
  const float* embed_w = (const float*)d_in[9];
  const float* embed_b = (const float*)d_in[10];
  const float* l1w[3]  = {(const float*)d_in[11], (const float*)d_in[13], (const float*)d_in[15]};
  const float* l1b[3]  = {(const float*)d_in[12], (const float*)d_in[14], (const float*)d_in[16]};
  const float* l2w[3]  = {(const float*)d_in[17], (const float*)d_in[19], (const float*)d_in[21]};
  const float* l2b[3]  = {(const float*)d_in[18], (const float*)d_in[20], (const float*)d_in[22]};
  const float* attn_w1 = (const float*)d_in[23];
  const float* attn_b1 = (const float*)d_in[24];
  const float* attn_w2 = (const float*)d_in[25];
  const float* pred_w  = (const float*)d_in[26];
  const float* pred_b  = (const float*)d_in[27];
  float* out = (float*)d_out;

  const int N0 = in_sizes[0] / 128;
  const int N1 = in_sizes[4];
  const int N2 = out_size;
  const int E0 = in_sizes[5] / 3;
  const int E1 = in_sizes[7] / 3;

  char* wp = (char*)d_ws;
  auto walloc = [&](size_t bytes) {
    char* p = wp; wp += (bytes + 255) & ~(size_t)255; return p;
  };
  // Fixed allocations (~117 MB)
  ushort* feat0  = (ushort*)walloc((size_t)N0 * 256 * 2);      // bf16
  ushort* inp    = (ushort*)walloc((size_t)3 * N1 * 256 * 2);  // bf16
  float*  z      = (float*)walloc((size_t)3 * N1 * 128 * 4);   // fp32
  ushort* wt_emb = (ushort*)walloc((size_t)128 * 128 * 2);
  ushort* wt_attn = (ushort*)walloc((size_t)128 * 128 * 2);
  ushort* wt_fc1[2], *wt_fc2[2], *wt_fc3[2];
  for (int l = 0; l < 2; ++l) {
    wt_fc1[l] = (ushort*)walloc((size_t)3 * 256 * 128 * 2);
    wt_fc2[l] = (ushort*)walloc((size_t)3 * 768 * 128 * 2);
    wt_fc3[l] = (ushort*)walloc((size_t)3 * 256 * 128 * 2);
  }
  int*   degcnt = (int*)walloc((size_t)3 * N1 * 4);
  int*   rowptr = (int*)walloc((size_t)3 * (N1 + 1) * 4);
  int*   csr    = (int*)walloc((size_t)3 * E0 * 4);
  float* small  = (float*)walloc(256);
  float* wsum = small;
  float* beta = small + 4;
  ushort* feat1 = feat0;

  // Adaptive agg chunk size (bf16 agg buffers)
  size_t used = (size_t)(wp - (char*)d_ws);
  size_t avail = (ws_size > used + 65536) ? (ws_size - used - 65536) : 0;
  const size_t per_row = (size_t)3 * (2 * 256 * 2 + 4 + 64);
  int CH = (int)(avail / per_row);
  if (CH > N1) CH = N1;
  if (CH < 1024) CH = 1024;
  ushort* aggS   = (ushort*)walloc((size_t)3 * CH * 256 * 2);
  ushort* aggM   = (ushort*)walloc((size_t)3 * CH * 256 * 2);
  float*  invdeg = (float*)walloc((size_t)3 * CH * 4);
  (void)n_in;

  // ---- weight prep: 8 tensors in one launch ----
  {
    PrepAll P;
    P.src[0] = embed_w;  P.dst[0] = wt_emb;    P.K[0] = 128; P.total[0] = 128 * 128;
    P.src[1] = attn_w1;  P.dst[1] = wt_attn;   P.K[1] = 128; P.total[1] = 128 * 128;
    P.src[2] = l1w[0];   P.dst[2] = wt_fc1[0]; P.K[2] = 256; P.total[2] = 3 * 256 * 128;
    P.src[3] = l1w[1];   P.dst[3] = wt_fc2[0]; P.K[3] = 768; P.total[3] = 3 * 768 * 128;
    P.src[4] = l1w[2];   P.dst[4] = wt_fc3[0]; P.K[4] = 256; P.total[4] = 3 * 256 * 128;
    P.src[5] = l2w[0];   P.dst[5] = wt_fc1[1]; P.K[5] = 256; P.total[5] = 3 * 256 * 128;
    P.src[6] = l2w[1];   P.dst[6] = wt_fc2[1]; P.K[6] = 768; P.total[6] = 3 * 768 * 128;
    P.src[7] = l2w[2];   P.dst[7] = wt_fc3[1]; P.K[7] = 256; P.total[7] = 3 * 256 * 128;
    prep_all<<<dim3((3 * 768 * 128 + 255) / 256, 1, 8), 256, 0, stream>>>(P);
  }

  GemmDesc dz = {};
  dz.K = 256;   // benign default for the unused descriptor slot

  // ---- feat0 = bf16[x@embed | tss | rs] (gather fused into epilogue) ----
  {
    GemmDesc d{};
    d.A = x_user; d.lda = 128; d.aStride = 0; d.aKind = 0;
    d.Wt = wt_emb; d.wStride = 0; d.bias = embed_b; d.biasStride = 0;
    d.C = feat0; d.ldc = 256; d.cStride = 0; d.cKind = 1;
    d.M = N0; d.K = 128; d.relu = 0;
    d.aggM = aggM; d.aggS = aggS; d.invdeg = invdeg; d.aggStride = 0; d.invStride = 0;
    d.gnid = src_nid0; d.gtss = tss; d.grs = rs;
    gemm_mfma<<<dim3((N0 + 63) / 64, 1, 1), 256, 0, stream>>>(d, dz);
  }

  // ---- two conv layers ----
  for (int layer = 0; layer < 2; ++layer) {
    const ushort* featS = layer ? feat1 : feat0;
    int Nd = layer ? N2 : N1;
    int E  = layer ? E1 : E0;
    const int* es = layer ? e1_src : e0_src;
    const int* ed = layer ? e1_dst : e0_dst;
    const float* const* lb = layer ? l2b : l1b;

    // CSR build for all 3 relations (per-relation rowptr/scan)
    hipMemsetAsync(degcnt, 0, (size_t)3 * Nd * 4, stream);
    count_deg<<<dim3((E + 255) / 256, 3), 256, 0, stream>>>(ed, E, Nd, degcnt);
    scan_kernel<<<dim3(1, 3), 1024, 0, stream>>>(degcnt, rowptr, degcnt, Nd);
    fill_csr<<<dim3((E + 255) / 256, 3), 256, 0, stream>>>(es, ed, E, Nd, rowptr, degcnt, csr);

    // chunked: agg -> fused fc2 (z=0, K=768 virtual) + fc1 (z=1, K=256)
    for (int c0 = 0; c0 < Nd; c0 += CH) {
      int cr = (Nd - c0 < CH) ? (Nd - c0) : CH;
      agg_kernel<<<dim3((cr + 3) / 4, 3), 256, 0, stream>>>(
          featS, csr, rowptr, Nd, c0, cr, CH, E, aggS, aggM, invdeg);
      GemmDesc d2{};
      d2.A = nullptr; d2.lda = 0; d2.aStride = 0; d2.aKind = 2;
      d2.Wt = wt_fc2[layer]; d2.wStride = (size_t)768 * 128; d2.bias = lb[1]; d2.biasStride = 128;
      d2.C = inp + (size_t)c0 * 256; d2.ldc = 256; d2.cStride = (size_t)Nd * 256; d2.cKind = 1;
      d2.M = cr; d2.K = 768; d2.relu = 1;
      d2.aggM = aggM; d2.aggS = aggS; d2.invdeg = invdeg;
      d2.aggStride = (size_t)CH * 256; d2.invStride = CH;
      GemmDesc d1{};
      d1.A = featS + (size_t)c0 * 256; d1.lda = 256; d1.aStride = 0; d1.aKind = 1;
      d1.Wt = wt_fc1[layer]; d1.wStride = (size_t)256 * 128; d1.bias = lb[0]; d1.biasStride = 128;
      d1.C = inp + 128 + (size_t)c0 * 256; d1.ldc = 256; d1.cStride = (size_t)Nd * 256; d1.cKind = 1;
      d1.M = cr; d1.K = 256; d1.relu = 1;
      d1.aggM = aggM; d1.aggS = aggS; d1.invdeg = invdeg; d1.aggStride = 0; d1.invStride = 0;
      gemm_mfma<<<dim3((cr + 63) / 64, 3, 2), 256, 0, stream>>>(d2, d1);
    }

    // fused fc3 + attention (wsum must be zeroed first)
    hipMemsetAsync(wsum, 0, 3 * sizeof(float), stream);
    fc3_attn<<<dim3((Nd + 63) / 64, 3), 256, 0, stream>>>(
        inp, (size_t)Nd * 256, wt_fc3[layer], (size_t)256 * 128, lb[2],
        z, (size_t)Nd * 128, Nd, wt_attn, attn_b1, attn_w2, wsum);
    beta_kernel<<<1, 1, 0, stream>>>(wsum, 1.0f / (float)Nd, beta);

    if (layer == 0) {
      combine1_kernel<<<N1, 256, 0, stream>>>(z, beta, tss, rs, src_nid1, N1, feat1);
    } else {
      combine2_pred<<<N2, 128, 0, stream>>>(z, beta, N2, pred_w, pred_b, out);
    }
  }
}